// Round 1
// 270.393 us; speedup vs baseline: 1.0499x; 1.0499x over previous
//
#include <hip/hip_runtime.h>

// HairBundleSDE: dx = f(t, x) elementwise, N=8388608 rows x 5 f32 state vars.
// Traffic 335.5MB logical => ~53us floor at 6.3 TB/s achievable.
//
// R6: wave-synchronous restructuring of the R5 LDS-staging kernel.
//  - Each WAVE stages the 320 float4 (5KB) covering its own 256 rows:
//    global->LDS lane-consecutive, then lane-private row gather (thread t
//    owns floats [20t, 20t+20) of the window), compute, scatter IN PLACE
//    (gather region == scatter region per lane), then LDS->global
//    lane-consecutive.
//  - Consequence 1: ZERO __syncthreads. The old version paid two full-block
//    s_waitcnt vmcnt(0)+s_barrier drains per chunk; waves now stream
//    independently with only per-wave compiler-inserted waitcnts.
//  - Consequence 2: one 20KB buffer instead of two (in-place scatter) ->
//    LDS allows 8 blocks/CU = 32 waves/CU (was 4 blocks / 16 waves).
//  - LDS row stride = 20 floats: within each 8-lane group the b128 gather
//    tiles all 32 banks exactly once -> conflict-free (unchanged from R5).
//  - Nontemporal load/store hints: both streams are touched exactly once,
//    no L2 reuse exists.
// Block = 256 threads <-> 1024 rows, grid = 8192 blocks (exactly N/1024).

namespace {

typedef float f32x4 __attribute__((ext_vector_type(4)));

constexpr float K_GS      = 0.75f;
constexpr float K_SP      = 0.6f;
constexpr float D0        = 0.5f;
constexpr float DELTA_INV = 5.0f;   // 1/0.2
constexpr float F_MAX     = 1.0f;
constexpr float S_CA      = 0.7f;
constexpr float LAMA_INV  = 0.1f;   // 1/LAM_A
constexpr float AMP       = 0.3f;
constexpr float OMEGA     = 6.283185307179586f;

constexpr int BLOCK       = 256;
constexpr int ROWS_PER_T  = 4;
constexpr int CHUNK_ROWS  = BLOCK * ROWS_PER_T;          // 1024 rows/block
constexpr int CHUNK_F4    = CHUNK_ROWS * 5 / 4;          // 1280 f32x4 = 20KB
constexpr int WAVE_F4     = 64 * ROWS_PER_T * 5 / 4;     // 320 f32x4 = 5KB/wave

__device__ __forceinline__ void compute_row(float X, float Xa, float pm, float pgs, float pt,
                                            float force, float* o) {
    float d   = X - Xa;
    float z   = (d - D0) * DELTA_INV;
    float p   = 1.0f / (1.0f + __expf(-z));          // sigmoid((X-Xa-D0)/DELTA)
    float fgs = K_GS * (d - D0 * p);
    o[0] = force - fgs - K_SP * X;                   // dX   (LAM = 1)
    o[1] = (fgs - (F_MAX - S_CA * pm)) * LAMA_INV;   // dXa
    o[2] = 1.5f * p * (1.0f - pm) - pm;              // dpm  (TAU_M = 1)
    o[3] = (1.2f * p * (1.0f - pgs) - pgs) * 0.2f;   // dpgs (TAU_GS = 5)
    o[4] = (0.8f * p * (1.0f - pt)  - pt)  * 0.1f;   // dpt  (TAU_T = 10)
}

} // namespace

__global__ __launch_bounds__(BLOCK) void hb_kernel(
        const float* __restrict__ tp,
        const float* __restrict__ xp,
        float* __restrict__ op,
        long long nrows) {
    __shared__ f32x4 s[CHUNK_F4];   // 20 KB, four wave-private 5KB windows

    const int tid   = threadIdx.x;
    const int lane  = tid & 63;
    const int wbase = (tid >> 6) * WAVE_F4;     // this wave's f32x4 window base

    const long long chunk0 = (long long)blockIdx.x * CHUNK_ROWS;

    // force = AMP * sin(OMEGA * t); one sinf per thread, fully hidden.
    const float force = AMP * sinf(OMEGA * tp[0]);

    if (chunk0 + CHUNK_ROWS <= nrows) {
        const f32x4* gsrc = reinterpret_cast<const f32x4*>(xp + chunk0 * 5) + wbase;
        f32x4*       gdst = reinterpret_cast<f32x4*>(op + chunk0 * 5)       + wbase;
        f32x4*       sw   = s + wbase;

        // ---- stage 1: wave-coalesced global -> LDS (wave-private window) ----
#pragma unroll
        for (int k = 0; k < 5; ++k)
            sw[64 * k + lane] = __builtin_nontemporal_load(gsrc + 64 * k + lane);

        __builtin_amdgcn_wave_barrier();   // compile-time ordering only; free

        // ---- stage 2: lane-private row gather (80B/lane, bank-conflict-free:
        //      20-float stride -> each 8-lane group tiles all 32 banks),
        //      compute 4 rows, scatter results IN PLACE ----
        f32x4* r4 = reinterpret_cast<f32x4*>(reinterpret_cast<float*>(sw) + lane * 20);

        float vals[20];
#pragma unroll
        for (int k = 0; k < 5; ++k) {
            f32x4 v = r4[k];
            vals[4*k+0] = v.x; vals[4*k+1] = v.y; vals[4*k+2] = v.z; vals[4*k+3] = v.w;
        }

#pragma unroll
        for (int r = 0; r < ROWS_PER_T; ++r)    // args pass by value -> safe in-place
            compute_row(vals[5*r+0], vals[5*r+1], vals[5*r+2], vals[5*r+3], vals[5*r+4],
                        force, &vals[5*r]);

#pragma unroll
        for (int k = 0; k < 5; ++k)
            r4[k] = (f32x4){vals[4*k+0], vals[4*k+1], vals[4*k+2], vals[4*k+3]};

        __builtin_amdgcn_wave_barrier();   // compile-time ordering only; free

        // ---- stage 3: wave-coalesced LDS -> global ----
#pragma unroll
        for (int k = 0; k < 5; ++k)
            __builtin_nontemporal_store(sw[64 * k + lane], gdst + 64 * k + lane);
    } else {
        // ---- tail path (not taken for N=8388608, kept for robustness) ----
        for (long long r = chunk0 + tid * ROWS_PER_T;
             r < nrows && r < chunk0 + (long long)(tid + 1) * ROWS_PER_T; ++r) {
            float in[5], out[5];
            for (int j = 0; j < 5; ++j) in[j] = xp[r*5 + j];
            compute_row(in[0], in[1], in[2], in[3], in[4], force, out);
            for (int j = 0; j < 5; ++j) op[r*5 + j] = out[j];
        }
    }
}

extern "C" void kernel_launch(void* const* d_in, const int* in_sizes, int n_in,
                              void* d_out, int out_size, void* d_ws, size_t ws_size,
                              hipStream_t stream) {
    const float* t = (const float*)d_in[0];
    const float* x = (const float*)d_in[1];
    float* out     = (float*)d_out;

    const long long nrows = (long long)in_sizes[1] / 5;            // 8388608
    const int grid = (int)((nrows + CHUNK_ROWS - 1) / CHUNK_ROWS); // 8192

    hb_kernel<<<grid, BLOCK, 0, stream>>>(t, x, out, nrows);
}